// Round 1
// baseline (13.626 us; speedup 1.0000x reference)
//
#include <hip/hip_runtime.h>

// BoundaryLoss collapses analytically:
//   boundary = min(edt(~mask), edt(mask)) == 0 at EVERY pixel
//   (each pixel is a feature pixel of one of the two sets, where its EDT is 0),
//   so weights == 1.0 exactly and the op is mean(BCE(inputs, targets)).

static constexpr int N_TOTAL = 32 * 320 * 320;   // 3,276,800
static constexpr int N4      = N_TOTAL / 4;      // 819,200 float4 elements
static constexpr int THREADS = 256;
static constexpr int BLOCKS  = 1024;             // grid-stride covers N4

__global__ __launch_bounds__(THREADS) void bce_partial_kernel(
    const float4* __restrict__ x4, const float4* __restrict__ t4,
    float* __restrict__ partial) {
    float acc = 0.0f;
    int tid    = blockIdx.x * THREADS + threadIdx.x;
    int stride = gridDim.x * THREADS;
    for (int i = tid; i < N4; i += stride) {
        float4 xv = x4[i];
        float4 tv = t4[i];
        float xs[4] = {xv.x, xv.y, xv.z, xv.w};
        float ts[4] = {tv.x, tv.y, tv.z, tv.w};
        #pragma unroll
        for (int j = 0; j < 4; ++j) {
            // p = sigmoid(x); robust for large |x| (expf saturates -> p in {0,1})
            float p   = 1.0f / (1.0f + expf(-xs[j]));
            float bce = -ts[j] * logf(p + 1e-6f)
                        - (1.0f - ts[j]) * logf(1.0f - p + 1e-6f);
            acc += bce;
        }
    }
    // wave (64-lane) shuffle reduction
    #pragma unroll
    for (int off = 32; off > 0; off >>= 1)
        acc += __shfl_down(acc, off, 64);
    __shared__ float sdata[THREADS / 64];
    int lane = threadIdx.x & 63;
    int wave = threadIdx.x >> 6;
    if (lane == 0) sdata[wave] = acc;
    __syncthreads();
    if (threadIdx.x == 0) {
        float s = 0.0f;
        #pragma unroll
        for (int w = 0; w < THREADS / 64; ++w) s += sdata[w];
        partial[blockIdx.x] = s;
    }
}

__global__ __launch_bounds__(THREADS) void final_reduce_kernel(
    const float* __restrict__ partial, float* __restrict__ out) {
    float acc = 0.0f;
    for (int i = threadIdx.x; i < BLOCKS; i += THREADS) acc += partial[i];
    #pragma unroll
    for (int off = 32; off > 0; off >>= 1)
        acc += __shfl_down(acc, off, 64);
    __shared__ float sdata[THREADS / 64];
    int lane = threadIdx.x & 63;
    int wave = threadIdx.x >> 6;
    if (lane == 0) sdata[wave] = acc;
    __syncthreads();
    if (threadIdx.x == 0) {
        float s = 0.0f;
        #pragma unroll
        for (int w = 0; w < THREADS / 64; ++w) s += sdata[w];
        out[0] = s / (float)N_TOTAL;
    }
}

extern "C" void kernel_launch(void* const* d_in, const int* in_sizes, int n_in,
                              void* d_out, int out_size, void* d_ws, size_t ws_size,
                              hipStream_t stream) {
    const float4* x4 = (const float4*)d_in[0];   // inputs  [32,1,320,320] f32
    const float4* t4 = (const float4*)d_in[1];   // targets [32,1,320,320] f32
    float* partial   = (float*)d_ws;             // BLOCKS floats of scratch
    float* out       = (float*)d_out;            // scalar f32

    bce_partial_kernel<<<BLOCKS, THREADS, 0, stream>>>(x4, t4, partial);
    final_reduce_kernel<<<1, THREADS, 0, stream>>>(partial, out);
}

// Round 2
// 13.273 us; speedup vs baseline: 1.0265x; 1.0265x over previous
//
#include <hip/hip_runtime.h>

// BoundaryLoss collapses analytically:
//   boundary = min(edt(~mask), edt(mask)) == 0 at EVERY pixel
//   (each pixel is a feature pixel of one of the two sets, where its EDT is 0),
//   so weights == 1.0 exactly and the op is mean(BCE(inputs, targets)).
//
// R2: fast transcendentals (__expf/__logf -> v_exp_f32/v_log_f32,
// __builtin_amdgcn_rcpf -> v_rcp_f32) instead of OCML precise routines +
// IEEE divide; uniform work (800 blocks x 256 thr x 4 float4 = N4 exactly).

static constexpr int N_TOTAL = 32 * 320 * 320;   // 3,276,800
static constexpr int N4      = N_TOTAL / 4;      // 819,200 float4 elements
static constexpr int THREADS = 256;
static constexpr int BLOCKS  = 800;              // 800*256*4 == N4 exactly
static constexpr int ITERS   = 4;

__global__ __launch_bounds__(THREADS) void bce_partial_kernel(
    const float4* __restrict__ x4, const float4* __restrict__ t4,
    float* __restrict__ partial) {
    const int tid    = blockIdx.x * THREADS + threadIdx.x;
    const int stride = BLOCKS * THREADS;

    float acc = 0.0f;
    #pragma unroll
    for (int it = 0; it < ITERS; ++it) {
        const int i = tid + it * stride;
        float4 xv = x4[i];
        float4 tv = t4[i];
        float xs[4] = {xv.x, xv.y, xv.z, xv.w};
        float ts[4] = {tv.x, tv.y, tv.z, tv.w};
        #pragma unroll
        for (int j = 0; j < 4; ++j) {
            float e = __expf(-xs[j]);                       // v_exp_f32
            float p = __builtin_amdgcn_rcpf(1.0f + e);      // v_rcp_f32 (sigmoid)
            float bce = -ts[j]          * __logf(p + 1e-6f)
                      - (1.0f - ts[j])  * __logf(1.0f - p + 1e-6f);
            acc += bce;
        }
    }

    // wave (64-lane) shuffle reduction
    #pragma unroll
    for (int off = 32; off > 0; off >>= 1)
        acc += __shfl_down(acc, off, 64);
    __shared__ float sdata[THREADS / 64];
    const int lane = threadIdx.x & 63;
    const int wave = threadIdx.x >> 6;
    if (lane == 0) sdata[wave] = acc;
    __syncthreads();
    if (threadIdx.x == 0) {
        float s = 0.0f;
        #pragma unroll
        for (int w = 0; w < THREADS / 64; ++w) s += sdata[w];
        partial[blockIdx.x] = s;
    }
}

__global__ __launch_bounds__(THREADS) void final_reduce_kernel(
    const float* __restrict__ partial, float* __restrict__ out) {
    float acc = 0.0f;
    for (int i = threadIdx.x; i < BLOCKS; i += THREADS) acc += partial[i];
    #pragma unroll
    for (int off = 32; off > 0; off >>= 1)
        acc += __shfl_down(acc, off, 64);
    __shared__ float sdata[THREADS / 64];
    const int lane = threadIdx.x & 63;
    const int wave = threadIdx.x >> 6;
    if (lane == 0) sdata[wave] = acc;
    __syncthreads();
    if (threadIdx.x == 0) {
        float s = 0.0f;
        #pragma unroll
        for (int w = 0; w < THREADS / 64; ++w) s += sdata[w];
        out[0] = s / (float)N_TOTAL;
    }
}

extern "C" void kernel_launch(void* const* d_in, const int* in_sizes, int n_in,
                              void* d_out, int out_size, void* d_ws, size_t ws_size,
                              hipStream_t stream) {
    const float4* x4 = (const float4*)d_in[0];   // inputs  [32,1,320,320] f32
    const float4* t4 = (const float4*)d_in[1];   // targets [32,1,320,320] f32
    float* partial   = (float*)d_ws;             // BLOCKS floats of scratch
    float* out       = (float*)d_out;            // scalar f32

    bce_partial_kernel<<<BLOCKS, THREADS, 0, stream>>>(x4, t4, partial);
    final_reduce_kernel<<<1, THREADS, 0, stream>>>(partial, out);
}